// Round 2
// 619.092 us; speedup vs baseline: 2.3116x; 2.3116x over previous
//
#include <hip/hip_runtime.h>

// Linformer attention on MI355X (gfx950) — ROUND 4: MFMA-fp16 stage 2 (compile fix).
// B=8 H=16 N=4096 DH=64 K=128 D=1024.
//
// R3 failed to COMPILE only: __builtin_amdgcn_cvt_pkrtz returns
// __fp16-vec2, not _Float16-vec2. All MFMA/layout code compiled. This round
// bit_casts every cvt_pkrtz result through unsigned and stores staged fp16
// as uint2v — bit-identical semantics, zero design change.
//
// Design (from R3):
//   dots:  D'[k][qrow] = KK·Q^T  (reduction dim dh is innermost in both) ->
//          each lane ends with 32 logits of ONE q-row (col=lane&15=qrow).
//   softmax: per-lane + shfl_xor(16/32). No logits-in-LDS at all.
//   PV:    VV transpose-staged once to vvt[dh][k] (k innermost) -> contiguous
//          B-frags; P relayout via cvt_pkrtz + shfl (element-wise verified).
// Stage 1 (lfa1_f32) byte-identical to the PASSING R2 kernel.
//
// Layout facts (from the reference's reshape-then-transpose):
//   q(b,h,n,dh)  = queries_flat[((b*4096 + n)*16 + h)*64 + dh]
//   kk(b,h,k,dh) = keys_p[b][k][h*64+dh],  vv likewise from vals_p
//   out(b,h,n,dh) -> out_flat[(b*4096+n)*1024 + h*64 + dh]
//
// MFMA 16x16x32 fragment facts used (guide §3, m89/m91-verified):
//   A-frag: lane holds A[row = l&15][kdim = (l>>4)*8 + j], j=0..7 (8 halves)
//   B-frag: lane holds B[kdim = (l>>4)*8 + j][col = l&15]
//   C/D   : lane reg r holds D[row = (l>>4)*4 + r][col = l&15]

#define Bb 8
#define Hh 16
#define Nn 4096
#define DHh 64
#define Kk 128
#define Dd 1024

typedef __attribute__((ext_vector_type(4))) float float4v;
typedef __attribute__((ext_vector_type(4))) float f32x4;
typedef __attribute__((ext_vector_type(8))) _Float16 half8;
typedef __attribute__((ext_vector_type(2))) unsigned int uint2v;
typedef __attribute__((ext_vector_type(4))) unsigned int u32x4;

// ---------------- stage 1: projection GEMMs (pure fp32, unchanged) ----------------
// out_p[b][k][d] = sum_n X[b][n][d] * P[n][k]
__global__ __launch_bounds__(256) void lfa1_f32(
    const float* __restrict__ keys, const float* __restrict__ values,
    const float* __restrict__ proj_k, const float* __restrict__ proj_v,
    float* __restrict__ kp, float* __restrict__ vp) {
  const bool vals = (int)blockIdx.x >= 256;
  const int id = (int)blockIdx.x & 255;
  const int b = id >> 5;                 // 0..7
  const int k0 = ((id >> 3) & 3) * 32;   // 0..96
  const int d0 = (id & 7) * 128;         // 0..896
  const float* __restrict__ Pg = vals ? proj_v : proj_k;                       // [4096][128]
  const float* __restrict__ Xg = (vals ? values : keys) + (size_t)b * Nn * Dd; // [4096][1024]
  float* __restrict__ dst = vals ? vp : kp;

  __shared__ alignas(16) float Ps[32 * 40];   // [n][k0..k0+32), stride 40
  __shared__ alignas(16) float Xs[32 * 136];  // [n][d0..d0+128), stride 136

  const int t = (int)threadIdx.x;
  const int kg = t >> 5;   // 0..7  -> k_local = kg*4 + a
  const int dg = t & 31;   // 0..31 -> d_local = dg*4 + c

  float acc[4][4];
#pragma unroll
  for (int a = 0; a < 4; ++a)
#pragma unroll
    for (int c = 0; c < 4; ++c) acc[a][c] = 0.f;

  float4v* const Ps4 = (float4v*)Ps;
  float4v* const Xs4 = (float4v*)Xs;

  for (int ck = 0; ck < Nn / 32; ++ck) {
    const int nb = ck * 32;
    {
      const int n = t >> 3, k4 = t & 7;
      Ps4[n * 10 + k4] = *(const float4v*)(Pg + (size_t)(nb + n) * Kk + k0 + k4 * 4);
#pragma unroll
      for (int i = 0; i < 4; ++i) {
        const int s = i * 256 + t;
        const int nx = s >> 5, d4 = s & 31;
        Xs4[nx * 34 + d4] = *(const float4v*)(Xg + (size_t)(nb + nx) * Dd + d0 + d4 * 4);
      }
    }
    __syncthreads();
#pragma unroll 8
    for (int n = 0; n < 32; ++n) {
      const float4v pv = Ps4[n * 10 + kg];
      const float4v xv = Xs4[n * 34 + dg];
#pragma unroll
      for (int a = 0; a < 4; ++a)
#pragma unroll
        for (int c = 0; c < 4; ++c) acc[a][c] = fmaf(pv[a], xv[c], acc[a][c]);
    }
    __syncthreads();
  }

#pragma unroll
  for (int a = 0; a < 4; ++a) {
    float4v o = {acc[a][0], acc[a][1], acc[a][2], acc[a][3]};
    *(float4v*)(dst + (size_t)(b * Kk + k0 + kg * 4 + a) * Dd + d0 + dg * 4) = o;
  }
}

// ---------------- stage 2: attention via MFMA fp16 ----------------
// grid 8192 = B*H*(N/64). block 256 = 4 waves; wave w owns q-rows w*16..+16.
#define KKS_STRIDE 72   // halves; row byte-stride 144 (16B-aligned)
#define VVT_STRIDE 136  // halves; row byte-stride 272 (16B-aligned)
#define QS_STRIDE 72

__global__ __launch_bounds__(256, 3) void lfa2_mfma(
    const float* __restrict__ q, const float* __restrict__ kp,
    const float* __restrict__ vp, float* __restrict__ out) {
  const int x = (int)blockIdx.x;
  const int n0 = (x & 63) * 64;
  const int h = (x >> 6) & 15;
  const int b = x >> 10;

  __shared__ alignas(16) _Float16 kks[Kk * KKS_STRIDE];   // [k][dh]   18432 B
  __shared__ alignas(16) _Float16 vvt[DHh * VVT_STRIDE];  // [dh][k]   17408 B
  __shared__ alignas(16) _Float16 qs[64 * QS_STRIDE];     // [row][dh]  9216 B

  const int t = (int)threadIdx.x;

  // ---- stage kk: fp32 -> fp16, natural [k][dh] ----
  {
    const int kq = t >> 4;         // 0..15
    const int dh0 = (t & 15) * 4;  // 0..60 (16 lanes cover 256B of a row: coalesced)
#pragma unroll
    for (int i = 0; i < 8; ++i) {
      const int k = i * 16 + kq;
      float4v v = *(const float4v*)(kp + ((size_t)(b * Kk + k)) * Dd + h * DHh + dh0);
      const unsigned p0 = __builtin_bit_cast(unsigned, __builtin_amdgcn_cvt_pkrtz(v[0], v[1]));
      const unsigned p1 = __builtin_bit_cast(unsigned, __builtin_amdgcn_cvt_pkrtz(v[2], v[3]));
      *(uint2v*)(kks + k * KKS_STRIDE + dh0) = (uint2v){p0, p1};
    }
    // ---- stage vv TRANSPOSED: vvt[dh][k] (k innermost for PV B-frags) ----
#pragma unroll
    for (int i = 0; i < 8; ++i) {
      const int k = i * 16 + kq;
      float4v v = *(const float4v*)(vp + ((size_t)(b * Kk + k)) * Dd + h * DHh + dh0);
#pragma unroll
      for (int e = 0; e < 4; ++e) vvt[(dh0 + e) * VVT_STRIDE + k] = (_Float16)v[e];
    }
  }
  // ---- stage q: scaled by dh^-0.5*log2(e), fp16 [row][dh] ----
  {
    const int r = t >> 2;
    const int c = t & 3;
    const float SC = 0.18033688011112042f;
#pragma unroll
    for (int i = 0; i < 4; ++i) {
      const int dh0 = c * 4 + i * 16;
      float4v v = *(const float4v*)(q + (((size_t)(b * Nn + n0 + r)) * Hh + h) * DHh + dh0);
      v *= SC;
      const unsigned p0 = __builtin_bit_cast(unsigned, __builtin_amdgcn_cvt_pkrtz(v[0], v[1]));
      const unsigned p1 = __builtin_bit_cast(unsigned, __builtin_amdgcn_cvt_pkrtz(v[2], v[3]));
      *(uint2v*)(qs + r * QS_STRIDE + dh0) = (uint2v){p0, p1};
    }
  }
  __syncthreads();  // only barrier in the kernel; waves run free afterwards

  const int l = t & 63;
  const int w = t >> 6;
  const int lr = l & 15;  // dots: qrow (D' col). PV: qrow (A row) / dh col.
  const int g = l >> 4;   // lane group 0..3

  // ---- dots: D'[k][qrow] += KK[k][dh] * Q[qrow][dh] over dh ----
  // B-frag (Q^T): lane reads Q[qrow=lr][dh = s*32 + g*8 + j] — contiguous b128.
  const half8 bq0 = *(const half8*)(qs + (w * 16 + lr) * QS_STRIDE + 0 * 32 + g * 8);
  const half8 bq1 = *(const half8*)(qs + (w * 16 + lr) * QS_STRIDE + 1 * 32 + g * 8);

  f32x4 acc[8];
#pragma unroll
  for (int kt = 0; kt < 8; ++kt) acc[kt] = (f32x4){0.f, 0.f, 0.f, 0.f};
#pragma unroll
  for (int kt = 0; kt < 8; ++kt) {
    // A-frag (KK): lane reads KK[kt*16+lr][dh = s*32 + g*8 + j] — contiguous b128.
    const half8 a0 = *(const half8*)(kks + (kt * 16 + lr) * KKS_STRIDE + 0 * 32 + g * 8);
    acc[kt] = __builtin_amdgcn_mfma_f32_16x16x32_f16(a0, bq0, acc[kt], 0, 0, 0);
    const half8 a1 = *(const half8*)(kks + (kt * 16 + lr) * KKS_STRIDE + 1 * 32 + g * 8);
    acc[kt] = __builtin_amdgcn_mfma_f32_16x16x32_f16(a1, bq1, acc[kt], 0, 0, 0);
  }
  // lane now holds logits (base-2 units) of qrow=lr at k = kt*16 + g*4 + r.

  // ---- softmax: row is spread over the 4 lanes sharing lr (g=0..3) ----
  float m = -3.4e38f;
#pragma unroll
  for (int kt = 0; kt < 8; ++kt)
#pragma unroll
    for (int r = 0; r < 4; ++r) m = fmaxf(m, acc[kt][r]);
  m = fmaxf(m, __shfl_xor(m, 16));
  m = fmaxf(m, __shfl_xor(m, 32));
  float s = 0.f;
#pragma unroll
  for (int kt = 0; kt < 8; ++kt)
#pragma unroll
    for (int r = 0; r < 4; ++r) {
      const float e = __builtin_amdgcn_exp2f(acc[kt][r] - m);
      acc[kt][r] = e;
      s += e;
    }
  s += __shfl_xor(s, 16);
  s += __shfl_xor(s, 32);
  const float inv = 1.f / s;

  // pack probs: pk[kt][dd] = fp16x2(p[k=kt*16+4g+2dd], p[k=..+2dd+1])
  unsigned pk[8][2];
#pragma unroll
  for (int kt = 0; kt < 8; ++kt) {
    pk[kt][0] = __builtin_bit_cast(
        unsigned, __builtin_amdgcn_cvt_pkrtz(acc[kt][0] * inv, acc[kt][1] * inv));
    pk[kt][1] = __builtin_bit_cast(
        unsigned, __builtin_amdgcn_cvt_pkrtz(acc[kt][2] * inv, acc[kt][3] * inv));
  }

  // ---- PV: C2[qrow][dh] += P[qrow][k] * VV[k][dh] over k ----
  // P A-frag relayout (verified element-wise): dest lane (g,lr) dword m holds
  // k = ks*32 + 8g + {2m,2m+1}; source = lane (2(g&1)+(m>>1))*16 + lr,
  // tile kt' = 2ks + (g>>1), packed dword (m&1).
  const int sl0 = ((l >> 4) & 1) * 32 + lr;  // g' = 2(g&1)
  const int sl1 = sl0 + 16;                  // g' = 2(g&1)+1
  const bool gh = (l & 32) != 0;             // g>>1 selects tile 2ks vs 2ks+1

  f32x4 o[4];
#pragma unroll
  for (int dt = 0; dt < 4; ++dt) o[dt] = (f32x4){0.f, 0.f, 0.f, 0.f};

#pragma unroll
  for (int ks = 0; ks < 4; ++ks) {
    const unsigned va0 = __shfl(pk[2 * ks][0], sl0);
    const unsigned vb0 = __shfl(pk[2 * ks + 1][0], sl0);
    const unsigned va1 = __shfl(pk[2 * ks][1], sl0);
    const unsigned vb1 = __shfl(pk[2 * ks + 1][1], sl0);
    const unsigned va2 = __shfl(pk[2 * ks][0], sl1);
    const unsigned vb2 = __shfl(pk[2 * ks + 1][0], sl1);
    const unsigned va3 = __shfl(pk[2 * ks][1], sl1);
    const unsigned vb3 = __shfl(pk[2 * ks + 1][1], sl1);
    const u32x4 w4 = {gh ? vb0 : va0, gh ? vb1 : va1, gh ? vb2 : va2, gh ? vb3 : va3};
    const half8 pa = __builtin_bit_cast(half8, w4);
#pragma unroll
    for (int dt = 0; dt < 4; ++dt) {
      // B-frag (VV): lane reads vvt[dh = dt*16+lr][k = ks*32 + g*8 + j] — contiguous b128.
      const half8 bv = *(const half8*)(vvt + (dt * 16 + lr) * VVT_STRIDE + ks * 32 + g * 8);
      o[dt] = __builtin_amdgcn_mfma_f32_16x16x32_f16(pa, bv, o[dt], 0, 0, 0);
    }
  }

  // ---- store: D2 row = g*4 + r (qrow in wave tile), col = dt*16 + lr (dh) ----
  float* const obase = out + ((size_t)(b * Nn + n0 + w * 16 + g * 4)) * Dd + h * DHh;
#pragma unroll
  for (int dt = 0; dt < 4; ++dt)
#pragma unroll
    for (int r = 0; r < 4; ++r)
      obase[(size_t)r * Dd + dt * 16 + lr] = o[dt][r];
}

extern "C" void kernel_launch(void* const* d_in, const int* in_sizes, int n_in,
                              void* d_out, int out_size, void* d_ws, size_t ws_size,
                              hipStream_t stream) {
  (void)in_sizes; (void)n_in; (void)out_size; (void)ws_size;
  const float* queries = (const float*)d_in[0];
  const float* keys = (const float*)d_in[1];
  const float* values = (const float*)d_in[2];
  const float* proj_k = (const float*)d_in[3];
  const float* proj_v = (const float*)d_in[4];
  float* out = (float*)d_out;

  // ws: kp fp32 [8][128][1024] (4MB) | vp fp32 (4MB)
  float* kp = (float*)d_ws;
  float* vp = kp + (size_t)Bb * Kk * Dd;

  hipLaunchKernelGGL(lfa1_f32, dim3(512), dim3(256), 0, stream,
                     keys, values, proj_k, proj_v, kp, vp);
  hipLaunchKernelGGL(lfa2_mfma, dim3(8192), dim3(256), 0, stream,
                     queries, kp, vp, out);
}